// Round 1
// 73.495 us; speedup vs baseline: 1.0186x; 1.0186x over previous
//
#include <hip/hip_runtime.h>

#define HOP      512
#define NHARM    100
#define TFRAMES  400
#define INV_SR   (1.0f / 44100.0f)
#define INV_2PI  0.15915494309189535f

// cos(2*pi*t), t in revolutions (v_fract + v_cos).
__device__ __forceinline__ float cos_rev(float t) {
    return __builtin_amdgcn_cosf(__builtin_amdgcn_fractf(t));
}

// TLP-first decomposition (vs prev round's 1024-sample / 4-wave blocks):
// one 512-thread block (8 waves) per 512-sample hop chunk q; out sample
// s = q*512 + r gets exactly two frames: A = q (x = r, window 0.5*(1+c))
// and B = q+1 (x = r-512 folded into phase, window 0.5*(1-c)),
// c = cos(2*pi*r/1024).  Harmonics split across the 8 waves (12-13 each),
// 8 consecutive samples per lane via Chebyshev recurrence.
// 1600 blocks x 8 waves = 12800 waves; __launch_bounds__(512,8) caps
// VGPR at 64 -> 4 blocks/CU = 8 waves/SIMD resident (vs 3.1 before).
__global__ __launch_bounds__(512, 8) void sinstack_kernel(
    const float* __restrict__ ampl,
    const float* __restrict__ phase,
    const float* __restrict__ f0,
    float* __restrict__ out)
{
    const int q    = blockIdx.x;   // 0..399 (hop chunk)
    const int b    = blockIdx.y;   // batch
    const int tid  = threadIdx.x;  // 0..511
    const int wave = tid >> 6;     // 0..7
    const int lane = tid & 63;

    // {ampl, fr (rev/sample), ph (rev, shift folded), 2*cos(2pi*fr)}
    __shared__ float4 sPar[2 * NHARM];
    // per-wave windowed partials, transposed + padded (65-float rows)
    __shared__ float  sOut[8 * 520];

    for (int i = tid; i < 2 * NHARM; i += 512) {
        const int k = (i >= NHARM);       // 0 -> frame q, 1 -> frame q+1
        const int n = i - k * NHARM;
        const int t = q + k;
        float4 par = make_float4(0.f, 0.f, 0.f, 2.f);
        if (t < TFRAMES) {
            const int idx = (b * NHARM + n) * TFRAMES + t;
            const float a  = ampl[idx];
            const float fr = f0[idx] * INV_SR;                 // rev/sample
            const float ph = phase[idx] * INV_2PI - (float)(512 * k) * fr;
            par = make_float4(a, fr, ph, 2.0f * cos_rev(fr));
        }
        sPar[i] = par;
    }
    __syncthreads();

    const float r0 = (float)(lane * 8);
    const float4* parA = sPar;
    const float4* parB = sPar + NHARM;
    const int n0 = (wave * NHARM) >> 3;        // 12/13 harmonics per wave
    const int n1 = ((wave + 1) * NHARM) >> 3;

    float aA[8], aB[8];
#pragma unroll
    for (int j = 0; j < 8; ++j) { aA[j] = 0.f; aB[j] = 0.f; }

    // rotating register prefetch keeps the LDS read off the critical path
    float4 pa = parA[n0];
    float4 pb = parB[n0];
    for (int n = n0; n < n1; ++n) {
        const int nn = (n + 1 < n1) ? (n + 1) : n0;
        const float4 paN = parA[nn];
        const float4 pbN = parB[nn];

        const float ta0 = fmaf(pa.y, r0, pa.z);
        const float tb0 = fmaf(pb.y, r0, pb.z);
        float aPrev = cos_rev(ta0);
        float bPrev = cos_rev(tb0);
        float aCur  = cos_rev(ta0 + pa.y);
        float bCur  = cos_rev(tb0 + pb.y);
        aA[0] = fmaf(pa.x, aPrev, aA[0]);
        aB[0] = fmaf(pb.x, bPrev, aB[0]);
        aA[1] = fmaf(pa.x, aCur,  aA[1]);
        aB[1] = fmaf(pb.x, bCur,  aB[1]);
#pragma unroll
        for (int j = 2; j < 8; ++j) {
            const float aN = fmaf(pa.w, aCur, -aPrev);
            const float bN = fmaf(pb.w, bCur, -bPrev);
            aA[j] = fmaf(pa.x, aN, aA[j]);
            aB[j] = fmaf(pb.x, bN, aB[j]);
            aPrev = aCur; aCur = aN;
            bPrev = bCur; bCur = bN;
        }
        pa = paN; pb = pbN;
    }

    // window (linear in partials -> per wave), transposed padded LDS write
    float* myOut = sOut + wave * 520 + lane;
#pragma unroll
    for (int j = 0; j < 8; ++j) {
        const float c = cos_rev((r0 + (float)j) * (1.0f / 1024.0f));
        myOut[j * 65] = 0.5f * ((aA[j] + aB[j]) + c * (aA[j] - aB[j]));
    }
    __syncthreads();

    // reduce 8 partials; thread t -> sample t, coalesced scalar store
    const int pos = (tid & 7) * 65 + (tid >> 3);   // inverse of transposed layout
    float v = sOut[pos];
#pragma unroll
    for (int w = 1; w < 8; ++w) v += sOut[w * 520 + pos];
    out[(size_t)b * (TFRAMES * HOP) + (size_t)q * HOP + tid] = v;
}

extern "C" void kernel_launch(void* const* d_in, const int* in_sizes, int n_in,
                              void* d_out, int out_size, void* d_ws, size_t ws_size,
                              hipStream_t stream) {
    const float* ampl  = (const float*)d_in[0];
    const float* phase = (const float*)d_in[1];
    const float* f0    = (const float*)d_in[2];
    float* out = (float*)d_out;

    const int B = in_sizes[0] / (NHARM * TFRAMES);  // = 4
    dim3 grid(TFRAMES, B);
    sinstack_kernel<<<grid, 512, 0, stream>>>(ampl, phase, f0, out);
}